// Round 12
// baseline (376.814 us; speedup 1.0000x reference)
//
#include <hip/hip_runtime.h>
#include <hip/hip_bf16.h>
#include <stdint.h>

#define IN_F 256
#define K_TOT 512
#define GR 64   // rows per block

typedef __attribute__((ext_vector_type(8))) _Float16 f16x8;
typedef __attribute__((ext_vector_type(4))) _Float16 f16x4;
typedef __attribute__((ext_vector_type(4))) float f32x4;
typedef __attribute__((ext_vector_type(2))) float f32x2;

#if __has_builtin(__builtin_amdgcn_cvt_pk_f32_fp8) && __has_builtin(__builtin_amdgcn_cvt_pk_fp8_f32)
#define HW_FP8 1
#endif

// ---- fp8 e4m3 helpers (HW cvt with software RNE fallback) ----
__device__ __forceinline__ float fp8_dec1(uint32_t b) {
  union { uint16_t u; _Float16 h; } cv;
  cv.u = (uint16_t)((b & 0x7F) << 7);
  float v = (float)cv.h * 256.0f;
  return (b & 0x80) ? -v : v;
}
__device__ __forceinline__ uint32_t fp8_enc1(float f) {
  union { _Float16 h; uint16_t u; } cv;
  cv.h = (_Float16)(f * (1.0f / 256.0f));
  uint32_t s = (cv.u >> 8) & 0x80;
  uint32_t t = cv.u & 0x7FFF;
  uint32_t r = (t + 0x3F + ((t >> 7) & 1)) >> 7;  // RNE at 3-bit mantissa
  if (r > 0x7E) r = 0x7E;                          // clamp to 448
  return s | r;
}
__device__ __forceinline__ void fp8x4_dec(uint32_t w, float4& o) {
#ifdef HW_FP8
  f32x2 lo = __builtin_amdgcn_cvt_pk_f32_fp8((int)w, false);
  f32x2 hi = __builtin_amdgcn_cvt_pk_f32_fp8((int)w, true);
  o.x = lo[0]; o.y = lo[1]; o.z = hi[0]; o.w = hi[1];
#else
  o.x = fp8_dec1(w & 0xFF); o.y = fp8_dec1((w >> 8) & 0xFF);
  o.z = fp8_dec1((w >> 16) & 0xFF); o.w = fp8_dec1(w >> 24);
#endif
}
__device__ __forceinline__ uint32_t fp8x4_enc(float a, float b, float c, float d) {
#ifdef HW_FP8
  int r = __builtin_amdgcn_cvt_pk_fp8_f32(a, b, 0, false);
  r = __builtin_amdgcn_cvt_pk_fp8_f32(c, d, r, true);
  return (uint32_t)r;
#else
  return fp8_enc1(a) | (fp8_enc1(b) << 8) | (fp8_enc1(c) << 16) | (fp8_enc1(d) << 24);
#endif
}

// ---- fused init: build Bhi | x->fp8 xq | zero counts | detect i64 ----
__global__ void init_kernel(const float* __restrict__ x,
                            const float* __restrict__ Ws,
                            const float* __restrict__ Wn,
                            const int* __restrict__ ei,
                            _Float16* __restrict__ Bhi,
                            uint32_t* __restrict__ xq,
                            int* __restrict__ counts,
                            int* __restrict__ flag, int N, int nconv, int nmem) {
  __shared__ int bad_s[256];
  const int b = blockIdx.x;
  const int t = threadIdx.x;
  if (b < 512) {
    int idx = b * 256 + t;  // 0..131071
    int j = idx >> 9;
    int k = idx & 511;
    float v = (k < IN_F) ? Ws[j * IN_F + k] : Wn[j * IN_F + (k - IN_F)];
    size_t addr = ((size_t)(k >> 5) * 256 + j) * 32 + (k & 31);
    Bhi[addr] = (_Float16)v;
  } else if (b < 512 + nconv) {
    size_t base = (size_t)(b - 512) * 4096 + (size_t)t * 16;
    size_t tot = (size_t)N * IN_F;
    if (base + 16 <= tot) {
      const float4* x4 = reinterpret_cast<const float4*>(x + base);
      float4 v0 = x4[0], v1 = x4[1], v2 = x4[2], v3 = x4[3];
      uint4 o;
      o.x = fp8x4_enc(v0.x, v0.y, v0.z, v0.w);
      o.y = fp8x4_enc(v1.x, v1.y, v1.z, v1.w);
      o.z = fp8x4_enc(v2.x, v2.y, v2.z, v2.w);
      o.w = fp8x4_enc(v3.x, v3.y, v3.z, v3.w);
      *reinterpret_cast<uint4*>(xq + base / 4) = o;
    }
  } else if (b < 512 + nconv + nmem) {
    int base = (b - 512 - nconv) * 1024 + t * 4;
#pragma unroll
    for (int j = 0; j < 4; ++j)
      if (base + j < N) counts[base + j] = 0;
  } else {
    int bad = 0;
#pragma unroll
    for (int p = 0; p < 8; ++p) {
      int i = t + p * 256;
      if (ei[2 * i + 1] != 0) bad = 1;
    }
    bad_s[t] = bad;
    __syncthreads();
    for (int s = 128; s > 0; s >>= 1) {
      if (t < s) bad_s[t] |= bad_s[t + s];
      __syncthreads();
    }
    if (t == 0) *flag = (bad_s[0] == 0) ? 1 : 0;
  }
}

__global__ void hist_kernel(const int* __restrict__ ei, const int* __restrict__ flag,
                            int* __restrict__ counts, int E) {
  int e = blockIdx.x * 256 + threadIdx.x;
  if (e >= E) return;
  int is64 = *flag;
  int dst = is64 ? ei[2 * (E + e)] : ei[E + e];
  atomicAdd(counts + dst, 1);
}

__global__ void scan1_kernel(const int* __restrict__ counts, int* __restrict__ offsets,
                             int* __restrict__ bsums, int N) {
  __shared__ int buf[1024];
  int t = threadIdx.x;
  int i = blockIdx.x * 1024 + t;
  int v = (i < N) ? counts[i] : 0;
  buf[t] = v;
  __syncthreads();
  for (int s = 1; s < 1024; s <<= 1) {
    int add = (t >= s) ? buf[t - s] : 0;
    __syncthreads();
    buf[t] += add;
    __syncthreads();
  }
  if (i < N) offsets[i] = buf[t] - v;
  if (t == 1023) bsums[blockIdx.x] = buf[1023];
}

__global__ void scan23_kernel(int* __restrict__ offsets, const int* __restrict__ bsums,
                              int* __restrict__ cursor, int N, int E, int nb) {
  __shared__ int sb[128];
  int t = threadIdx.x;
  int v = 0;
  if (t < 128) {
    v = (t < nb) ? bsums[t] : 0;
    sb[t] = v;
  }
  __syncthreads();
  for (int s = 1; s < 128; s <<= 1) {
    int add = 0;
    if (t < 128 && t >= s) add = sb[t - s];
    __syncthreads();
    if (t < 128) sb[t] += add;
    __syncthreads();
  }
  if (t < 128) sb[t] -= v;  // exclusive
  __syncthreads();
  int i = blockIdx.x * 256 + t;
  if (i < N) {
    int o = offsets[i] + sb[i >> 10];
    offsets[i] = o;
    cursor[i] = o;
  }
  if (i == 0) offsets[N] = E;
}

// XCD-bucketed CSR fill, 4B packed entries (src<<15 | w15).
__global__ void fill_kernel(const int* __restrict__ ei, const float* __restrict__ ew,
                            const int* __restrict__ flag, int* __restrict__ cursor,
                            uint32_t* __restrict__ edges, int E, int nper) {
  int q = blockIdx.x & 7;
  int e = (blockIdx.x >> 3) * 256 + threadIdx.x;
  if (e >= E) return;
  int is64 = *flag;
  int dst = is64 ? ei[2 * (E + e)] : ei[E + e];
  if (dst / nper != q) return;
  int src = is64 ? ei[2 * e] : ei[e];
  uint32_t w15 = (uint32_t)__float2int_rn(ew[e] * 32767.0f);
  int pos = atomicAdd(cursor + dst, 1);
  edges[pos] = ((uint32_t)src << 15) | w15;
}

// Fused aggregate + MFMA GEMM + L2-norm.
// Phase 1: each wave aggregates 16 of the block's 64 nodes (fp8 gather,
// 8-batched loads) -> f16 rows in neighT LDS tile (pad 264 -> 2-way = free).
// Phase 2: k-loop; ks 0..7 A-frags from x via double-buffered frag-major LDS
// (barrier only while dbuf active), ks 8..15 A-frags read straight from
// neighT (no barriers). B fragments register-prefetched 2 k-steps from L2.
__launch_bounds__(256)
__global__ void agg_gemm_kernel(const float* __restrict__ x,
                                const uint32_t* __restrict__ xq,
                                const int* __restrict__ offsets,
                                const uint32_t* __restrict__ edges,
                                const _Float16* __restrict__ Bhi,
                                const float* __restrict__ bias,
                                float* __restrict__ out, int N) {
  const int t = threadIdx.x;
  const int lane = t & 63;
  const int w = t >> 6;
  const int row0 = blockIdx.x * GR;

  __shared__ _Float16 neighT[GR][264];   // 33.8 KB
  __shared__ _Float16 Adb[2][256 * 8];   // 8 KB frag-major dbuf
  __shared__ float ssb[GR][4];

  // ---------- phase 1: aggregate ----------
  const float wscale = 1.0f / 32767.0f;
  for (int r = 0; r < 16; ++r) {
    int node = row0 + w * 16 + r;
    float4 acc = {0.f, 0.f, 0.f, 0.f};
    float ws = 0.f;
    if (node < N) {
      int beg = offsets[node];
      int end = offsets[node + 1];
      int e = beg;
      for (; e + 7 < end; e += 8) {
        uint32_t n[8];
#pragma unroll
        for (int j = 0; j < 8; ++j) n[j] = edges[e + j];
        uint32_t q[8];
#pragma unroll
        for (int j = 0; j < 8; ++j)
          q[j] = xq[(size_t)(n[j] >> 15) * 64 + lane];
#pragma unroll
        for (int j = 0; j < 8; ++j) {
          float wj = (float)(n[j] & 0x7FFF) * wscale;
          float4 fj;
          fp8x4_dec(q[j], fj);
          acc.x += fj.x * wj; acc.y += fj.y * wj;
          acc.z += fj.z * wj; acc.w += fj.w * wj;
          ws += wj;
        }
      }
      for (; e < end; ++e) {
        uint32_t n0 = edges[e];
        float w0 = (float)(n0 & 0x7FFF) * wscale;
        uint32_t q0 = xq[(size_t)(n0 >> 15) * 64 + lane];
        float4 f0;
        fp8x4_dec(q0, f0);
        acc.x += f0.x * w0; acc.y += f0.y * w0;
        acc.z += f0.z * w0; acc.w += f0.w * w0;
        ws += w0;
      }
      float inv = 1.f / fmaxf(ws, 1e-8f);
      acc.x *= inv; acc.y *= inv; acc.z *= inv; acc.w *= inv;
    }
    f16x4 o = {(_Float16)acc.x, (_Float16)acc.y, (_Float16)acc.z, (_Float16)acc.w};
    *reinterpret_cast<f16x4*>(&neighT[w * 16 + r][lane * 4]) = o;
  }

  // ---------- phase 2 prologue ----------
  f32x4 acc[4][4];
#pragma unroll
  for (int rt = 0; rt < 4; ++rt)
#pragma unroll
    for (int ct = 0; ct < 4; ++ct) acc[rt][ct] = (f32x4){0.f, 0.f, 0.f, 0.f};

  int st_row = row0 + (t >> 6) * 16 + (t & 15);
  if (st_row >= N) st_row = N - 1;
  const float* Ax = x + (size_t)st_row * IN_F + ((t >> 4) & 3) * 8;

  const size_t bfrag = (size_t)(w * 64 + (lane & 15)) * 32 + (lane >> 4) * 8;
  const _Float16* BhiP = Bhi + bfrag;
  // ct stride = 512 halves; ks stride = 8192 halves

  // A(ks=0) -> Adb[0]; A(ks=1) -> reg; B(0),B(1) -> regs
  {
    float4 va = *reinterpret_cast<const float4*>(Ax);
    float4 vb = *reinterpret_cast<const float4*>(Ax + 4);
    f16x8 hv = {(_Float16)va.x, (_Float16)va.y, (_Float16)va.z, (_Float16)va.w,
                (_Float16)vb.x, (_Float16)vb.y, (_Float16)vb.z, (_Float16)vb.w};
    *reinterpret_cast<f16x8*>(&Adb[0][t * 8]) = hv;
  }
  f16x8 a_next;
  {
    float4 va = *reinterpret_cast<const float4*>(Ax + 32);
    float4 vb = *reinterpret_cast<const float4*>(Ax + 36);
    a_next = (f16x8){(_Float16)va.x, (_Float16)va.y, (_Float16)va.z, (_Float16)va.w,
                     (_Float16)vb.x, (_Float16)vb.y, (_Float16)vb.z, (_Float16)vb.w};
  }
  f16x8 bH[2][4];
#pragma unroll
  for (int ct = 0; ct < 4; ++ct) {
    bH[0][ct] = *reinterpret_cast<const f16x8*>(BhiP + ct * 512);
    bH[1][ct] = *reinterpret_cast<const f16x8*>(BhiP + 8192 + ct * 512);
  }
  __syncthreads();  // covers neighT (all waves) + Adb[0]

  // ---------- phase 2 main loop ----------
#pragma unroll
  for (int ks = 0; ks < 16; ++ks) {
    f16x8 aH[4];
    if (ks < 8) {
#pragma unroll
      for (int rt = 0; rt < 4; ++rt)
        aH[rt] = *reinterpret_cast<const f16x8*>(&Adb[ks & 1][(rt * 64 + lane) * 8]);
    } else {
#pragma unroll
      for (int rt = 0; rt < 4; ++rt)
        aH[rt] = *reinterpret_cast<const f16x8*>(
            &neighT[rt * 16 + (lane & 15)][(ks - 8) * 32 + (lane >> 4) * 8]);
    }
    f16x8 bNext[4];
    if (ks < 14) {
#pragma unroll
      for (int ct = 0; ct < 4; ++ct)
        bNext[ct] = *reinterpret_cast<const f16x8*>(BhiP + (size_t)(ks + 2) * 8192 + ct * 512);
    }
    if (ks < 7)
      *reinterpret_cast<f16x8*>(&Adb[(ks + 1) & 1][t * 8]) = a_next;
    if (ks < 6) {
      float4 va = *reinterpret_cast<const float4*>(Ax + (size_t)(ks + 2) * 32);
      float4 vb = *reinterpret_cast<const float4*>(Ax + (size_t)(ks + 2) * 32 + 4);
      a_next = (f16x8){(_Float16)va.x, (_Float16)va.y, (_Float16)va.z, (_Float16)va.w,
                       (_Float16)vb.x, (_Float16)vb.y, (_Float16)vb.z, (_Float16)vb.w};
    }
#pragma unroll
    for (int ct = 0; ct < 4; ++ct)
#pragma unroll
      for (int rt = 0; rt < 4; ++rt)
        acc[rt][ct] = __builtin_amdgcn_mfma_f32_16x16x32_f16(aH[rt], bH[ks & 1][ct],
                                                             acc[rt][ct], 0, 0, 0);
    if (ks < 14) {
#pragma unroll
      for (int ct = 0; ct < 4; ++ct) bH[ks & 1][ct] = bNext[ct];
    }
    if (ks < 7) __syncthreads();
  }

  // ---------- epilogue: bias, row L2-norm, store ----------
  float bv[4];
#pragma unroll
  for (int ct = 0; ct < 4; ++ct) bv[ct] = bias[w * 64 + ct * 16 + (lane & 15)];

  __syncthreads();  // ssb reuse safety vs neighT phase? distinct buffers; for ssb writes below
#pragma unroll
  for (int rt = 0; rt < 4; ++rt)
#pragma unroll
    for (int i = 0; i < 4; ++i) {
      float ssv = 0.f;
#pragma unroll
      for (int ct = 0; ct < 4; ++ct) {
        float val = acc[rt][ct][i] + bv[ct];
        acc[rt][ct][i] = val;
        ssv += val * val;
      }
#pragma unroll
      for (int s = 1; s < 16; s <<= 1) ssv += __shfl_xor(ssv, s, 64);
      if ((lane & 15) == 0) ssb[rt * 16 + (lane >> 4) * 4 + i][w] = ssv;
    }
  __syncthreads();

#pragma unroll
  for (int rt = 0; rt < 4; ++rt)
#pragma unroll
    for (int i = 0; i < 4; ++i) {
      int rl = rt * 16 + (lane >> 4) * 4 + i;
      f32x4 s4 = *reinterpret_cast<const f32x4*>(&ssb[rl][0]);
      float ss = s4[0] + s4[1] + s4[2] + s4[3];
      int gr = row0 + rl;
      if (gr < N) {
        float scale = 1.0f / fmaxf(sqrtf(ss), 1e-12f);
#pragma unroll
        for (int ct = 0; ct < 4; ++ct)
          out[(size_t)gr * IN_F + w * 64 + ct * 16 + (lane & 15)] = acc[rt][ct][i] * scale;
      }
    }
}

extern "C" void kernel_launch(void* const* d_in, const int* in_sizes, int n_in,
                              void* d_out, int out_size, void* d_ws, size_t ws_size,
                              hipStream_t stream) {
  const float* x = (const float*)d_in[0];
  const int* ei = (const int*)d_in[1];
  const float* ew = (const float*)d_in[2];
  const float* Wself = (const float*)d_in[3];
  const float* Wneigh = (const float*)d_in[4];
  const float* bias = (const float*)d_in[5];
  float* out = (float*)d_out;

  const int N = in_sizes[0] / IN_F;
  const int E = in_sizes[2];

  // ws: Bhi | xq[N*64 u32] | edges[E u32] | counts[N] | offsets[N+1] |
  //     cursor[N] | bsums[128] | flag
  char* p = (char*)d_ws;
  _Float16* Bhi = (_Float16*)p;      p += (size_t)K_TOT * IN_F * 2;
  uint32_t* xq = (uint32_t*)p;       p += (size_t)N * IN_F;
  uint32_t* edges = (uint32_t*)p;    p += (size_t)E * 4;
  int* counts = (int*)p;             p += (size_t)N * 4;
  int* offsets = (int*)p;            p += (size_t)(N + 1) * 4;
  int* cursor = (int*)p;             p += (size_t)N * 4;
  int* bsums = (int*)p;              p += 128 * 4;
  int* flag = (int*)p;

  const int nconv = (int)(((size_t)N * IN_F + 4095) / 4096);
  const int nmem = (N + 1023) / 1024;
  const int nb = (N + 1023) / 1024;
  const int nper = (N + 7) / 8;  // nodes per XCD bucket

  init_kernel<<<512 + nconv + nmem + 1, 256, 0, stream>>>(
      x, Wself, Wneigh, ei, Bhi, xq, counts, flag, N, nconv, nmem);
  hist_kernel<<<(E + 255) / 256, 256, 0, stream>>>(ei, flag, counts, E);
  scan1_kernel<<<nb, 1024, 0, stream>>>(counts, offsets, bsums, N);
  scan23_kernel<<<(N + 255) / 256, 256, 0, stream>>>(offsets, bsums, cursor, N, E, nb);
  fill_kernel<<<((E + 255) / 256) * 8, 256, 0, stream>>>(ei, ew, flag, cursor, edges,
                                                         E, nper);
  agg_gemm_kernel<<<(N + GR - 1) / GR, 256, 0, stream>>>(x, xq, offsets, edges, Bhi,
                                                         bias, out, N);
}

// Round 13
// 331.592 us; speedup vs baseline: 1.1364x; 1.1364x over previous
//
#include <hip/hip_runtime.h>
#include <hip/hip_bf16.h>
#include <stdint.h>

#define IN_F 256
#define K_TOT 512
#define GR 64   // rows per gemm block

typedef __attribute__((ext_vector_type(8))) _Float16 f16x8;
typedef __attribute__((ext_vector_type(4))) _Float16 f16x4;
typedef __attribute__((ext_vector_type(4))) float f32x4;
typedef __attribute__((ext_vector_type(2))) float f32x2;

#if __has_builtin(__builtin_amdgcn_cvt_pk_f32_fp8) && __has_builtin(__builtin_amdgcn_cvt_pk_fp8_f32)
#define HW_FP8 1
#endif

// ---- fp8 e4m3 helpers (HW cvt with software RNE fallback) ----
__device__ __forceinline__ float fp8_dec1(uint32_t b) {
  union { uint16_t u; _Float16 h; } cv;
  cv.u = (uint16_t)((b & 0x7F) << 7);
  float v = (float)cv.h * 256.0f;
  return (b & 0x80) ? -v : v;
}
__device__ __forceinline__ uint32_t fp8_enc1(float f) {
  union { _Float16 h; uint16_t u; } cv;
  cv.h = (_Float16)(f * (1.0f / 256.0f));
  uint32_t s = (cv.u >> 8) & 0x80;
  uint32_t t = cv.u & 0x7FFF;
  uint32_t r = (t + 0x3F + ((t >> 7) & 1)) >> 7;  // RNE at 3-bit mantissa
  if (r > 0x7E) r = 0x7E;                          // clamp to 448
  return s | r;
}
__device__ __forceinline__ void fp8x4_dec(uint32_t w, float4& o) {
#ifdef HW_FP8
  f32x2 lo = __builtin_amdgcn_cvt_pk_f32_fp8((int)w, false);
  f32x2 hi = __builtin_amdgcn_cvt_pk_f32_fp8((int)w, true);
  o.x = lo[0]; o.y = lo[1]; o.z = hi[0]; o.w = hi[1];
#else
  o.x = fp8_dec1(w & 0xFF); o.y = fp8_dec1((w >> 8) & 0xFF);
  o.z = fp8_dec1((w >> 16) & 0xFF); o.w = fp8_dec1(w >> 24);
#endif
}
__device__ __forceinline__ uint32_t fp8x4_enc(float a, float b, float c, float d) {
#ifdef HW_FP8
  int r = __builtin_amdgcn_cvt_pk_fp8_f32(a, b, 0, false);
  r = __builtin_amdgcn_cvt_pk_fp8_f32(c, d, r, true);
  return (uint32_t)r;
#else
  return fp8_enc1(a) | (fp8_enc1(b) << 8) | (fp8_enc1(c) << 16) | (fp8_enc1(d) << 24);
#endif
}

// ---- fused init: build Bhi | x->(fp8 xq + f16 Af16 cols 0..255) | hist
//      (self-detecting i64) | detect i64 flag (for fill) ----
// counts zeroed by hipMemsetAsync before this kernel.
__global__ void init_kernel(const float* __restrict__ x,
                            const float* __restrict__ Ws,
                            const float* __restrict__ Wn,
                            const int* __restrict__ ei,
                            _Float16* __restrict__ Bhi,
                            uint32_t* __restrict__ xq, _Float16* __restrict__ Af16,
                            int* __restrict__ counts,
                            int* __restrict__ flag, int N, int E,
                            int nconv, int nhist) {
  __shared__ int bad_s[256];
  const int b = blockIdx.x;
  const int t = threadIdx.x;
  if (b < 512) {
    int idx = b * 256 + t;  // 0..131071
    int j = idx >> 9;
    int k = idx & 511;
    float v = (k < IN_F) ? Ws[j * IN_F + k] : Wn[j * IN_F + (k - IN_F)];
    size_t addr = ((size_t)(k >> 5) * 256 + j) * 32 + (k & 31);
    Bhi[addr] = (_Float16)v;
  } else if (b < 512 + nconv) {
    size_t base = (size_t)(b - 512) * 4096 + (size_t)t * 16;
    size_t tot = (size_t)N * IN_F;
    if (base + 16 <= tot) {
      const float4* x4 = reinterpret_cast<const float4*>(x + base);
      float4 v0 = x4[0], v1 = x4[1], v2 = x4[2], v3 = x4[3];
      uint4 o;
      o.x = fp8x4_enc(v0.x, v0.y, v0.z, v0.w);
      o.y = fp8x4_enc(v1.x, v1.y, v1.z, v1.w);
      o.z = fp8x4_enc(v2.x, v2.y, v2.z, v2.w);
      o.w = fp8x4_enc(v3.x, v3.y, v3.z, v3.w);
      *reinterpret_cast<uint4*>(xq + base / 4) = o;
      size_t row = base >> 8;
      int col = (int)(base & 255);
      f16x8 h0 = {(_Float16)v0.x, (_Float16)v0.y, (_Float16)v0.z, (_Float16)v0.w,
                  (_Float16)v1.x, (_Float16)v1.y, (_Float16)v1.z, (_Float16)v1.w};
      f16x8 h1 = {(_Float16)v2.x, (_Float16)v2.y, (_Float16)v2.z, (_Float16)v2.w,
                  (_Float16)v3.x, (_Float16)v3.y, (_Float16)v3.z, (_Float16)v3.w};
      _Float16* dst = Af16 + row * K_TOT + col;
      *reinterpret_cast<f16x8*>(dst) = h0;
      *reinterpret_cast<f16x8*>(dst + 8) = h1;
    }
  } else if (b < 512 + nconv + nhist) {
    // hist with per-block self-detection (samples the first 2048 pairs;
    // identical data for all blocks -> deterministic agreement).
    int bad = 0;
#pragma unroll
    for (int p = 0; p < 8; ++p)
      if (ei[2 * (t + p * 256) + 1] != 0) bad = 1;
    bad_s[t] = bad;
    __syncthreads();
    for (int s = 128; s > 0; s >>= 1) {
      if (t < s) bad_s[t] |= bad_s[t + s];
      __syncthreads();
    }
    int is64 = (bad_s[0] == 0);
    int e = (b - 512 - nconv) * 256 + t;
    if (e < E) {
      int dst = is64 ? ei[2 * (E + e)] : ei[E + e];
      atomicAdd(counts + dst, 1);
    }
  } else {
    int bad = 0;
#pragma unroll
    for (int p = 0; p < 8; ++p) {
      int i = t + p * 256;
      if (ei[2 * i + 1] != 0) bad = 1;
    }
    bad_s[t] = bad;
    __syncthreads();
    for (int s = 128; s > 0; s >>= 1) {
      if (t < s) bad_s[t] |= bad_s[t + s];
      __syncthreads();
    }
    if (t == 0) *flag = (bad_s[0] == 0) ? 1 : 0;
  }
}

__global__ void scan1_kernel(const int* __restrict__ counts, int* __restrict__ offsets,
                             int* __restrict__ bsums, int N) {
  __shared__ int buf[1024];
  int t = threadIdx.x;
  int i = blockIdx.x * 1024 + t;
  int v = (i < N) ? counts[i] : 0;
  buf[t] = v;
  __syncthreads();
  for (int s = 1; s < 1024; s <<= 1) {
    int add = (t >= s) ? buf[t - s] : 0;
    __syncthreads();
    buf[t] += add;
    __syncthreads();
  }
  if (i < N) offsets[i] = buf[t] - v;
  if (t == 1023) bsums[blockIdx.x] = buf[1023];
}

__global__ void scan23_kernel(int* __restrict__ offsets, const int* __restrict__ bsums,
                              int* __restrict__ cursor, int N, int E, int nb) {
  __shared__ int sb[128];
  int t = threadIdx.x;
  int v = 0;
  if (t < 128) {
    v = (t < nb) ? bsums[t] : 0;
    sb[t] = v;
  }
  __syncthreads();
  for (int s = 1; s < 128; s <<= 1) {
    int add = 0;
    if (t < 128 && t >= s) add = sb[t - s];
    __syncthreads();
    if (t < 128) sb[t] += add;
    __syncthreads();
  }
  if (t < 128) sb[t] -= v;  // exclusive
  __syncthreads();
  int i = blockIdx.x * 256 + t;
  if (i < N) {
    int o = offsets[i] + sb[i >> 10];
    offsets[i] = o;
    cursor[i] = o;
  }
  if (i == 0) offsets[N] = E;
}

// XCD-bucketed CSR fill, 4B packed entries (src<<15 | w15).
__global__ void fill_kernel(const int* __restrict__ ei, const float* __restrict__ ew,
                            const int* __restrict__ flag, int* __restrict__ cursor,
                            uint32_t* __restrict__ edges, int E, int nper) {
  int q = blockIdx.x & 7;
  int e = (blockIdx.x >> 3) * 256 + threadIdx.x;
  if (e >= E) return;
  int is64 = *flag;
  int dst = is64 ? ei[2 * (E + e)] : ei[E + e];
  if (dst / nper != q) return;
  int src = is64 ? ei[2 * e] : ei[e];
  uint32_t w15 = (uint32_t)__float2int_rn(ew[e] * 32767.0f);
  int pos = atomicAdd(cursor + dst, 1);
  edges[pos] = ((uint32_t)src << 15) | w15;
}

// One wave per dst node, fp8 gather; writes f16 result into Af16 cols 256..511.
__launch_bounds__(256)
__global__ void aggregate_fp8_kernel(const uint32_t* __restrict__ xq,
                                     const int* __restrict__ offsets,
                                     const uint32_t* __restrict__ edges,
                                     _Float16* __restrict__ Af16, int N) {
  int wid = blockIdx.x * 4 + (threadIdx.x >> 6);
  if (wid >= N) return;
  int lane = threadIdx.x & 63;
  int beg = offsets[wid];
  int end = offsets[wid + 1];
  float4 acc = {0.f, 0.f, 0.f, 0.f};
  float ws = 0.f;
  const float wscale = 1.0f / 32767.0f;
  int e = beg;
  for (; e + 3 < end; e += 4) {
    uint32_t n0 = edges[e], n1 = edges[e + 1], n2 = edges[e + 2], n3 = edges[e + 3];
    float w0 = (float)(n0 & 0x7FFF) * wscale, w1 = (float)(n1 & 0x7FFF) * wscale;
    float w2 = (float)(n2 & 0x7FFF) * wscale, w3 = (float)(n3 & 0x7FFF) * wscale;
    uint32_t q0 = xq[(size_t)(n0 >> 15) * 64 + lane];
    uint32_t q1 = xq[(size_t)(n1 >> 15) * 64 + lane];
    uint32_t q2 = xq[(size_t)(n2 >> 15) * 64 + lane];
    uint32_t q3 = xq[(size_t)(n3 >> 15) * 64 + lane];
    float4 f0, f1, f2, f3;
    fp8x4_dec(q0, f0); fp8x4_dec(q1, f1); fp8x4_dec(q2, f2); fp8x4_dec(q3, f3);
    acc.x += f0.x * w0 + f1.x * w1 + f2.x * w2 + f3.x * w3;
    acc.y += f0.y * w0 + f1.y * w1 + f2.y * w2 + f3.y * w3;
    acc.z += f0.z * w0 + f1.z * w1 + f2.z * w2 + f3.z * w3;
    acc.w += f0.w * w0 + f1.w * w1 + f2.w * w2 + f3.w * w3;
    ws += w0 + w1 + w2 + w3;
  }
  for (; e < end; ++e) {
    uint32_t n0 = edges[e];
    float w0 = (float)(n0 & 0x7FFF) * wscale;
    uint32_t q0 = xq[(size_t)(n0 >> 15) * 64 + lane];
    float4 f0;
    fp8x4_dec(q0, f0);
    acc.x += f0.x * w0; acc.y += f0.y * w0; acc.z += f0.z * w0; acc.w += f0.w * w0;
    ws += w0;
  }
  float inv = 1.f / fmaxf(ws, 1e-8f);
  f16x4 o = {(_Float16)(acc.x * inv), (_Float16)(acc.y * inv),
             (_Float16)(acc.z * inv), (_Float16)(acc.w * inv)};
  *reinterpret_cast<f16x4*>(Af16 + (size_t)wid * K_TOT + IN_F + lane * 4) = o;
}

// MFMA GEMM + L2-norm, barrier-free main loop: the block's WHOLE 64x512 f16
// A-panel (64KB) is staged frag-major in LDS once (1 barrier), then 16
// k-steps of {conflict-free ds_read_b128 + 2-deep B reg-prefetch from L2 +
// 16 MFMA} run with no synchronization. 2 blocks/CU (LDS-capped), waves
// fully independent.
__launch_bounds__(256)
__global__ void gemm_norm_kernel(const _Float16* __restrict__ Af16,
                                 const _Float16* __restrict__ Bhi,
                                 const float* __restrict__ bias,
                                 float* __restrict__ out, int N) {
  const int t = threadIdx.x;
  const int lane = t & 63;
  const int w = t >> 6;
  const int row0 = blockIdx.x * GR;

  __shared__ _Float16 Apan[4096 * 8];  // frag q=ks*256+rt*64+kseg*16+r15; 64KB
  __shared__ float ssb[GR][4];

  f32x4 acc[4][4];
#pragma unroll
  for (int rt = 0; rt < 4; ++rt)
#pragma unroll
    for (int ct = 0; ct < 4; ++ct) acc[rt][ct] = (f32x4){0.f, 0.f, 0.f, 0.f};

  int st_row = row0 + (t >> 6) * 16 + (t & 15);
  if (st_row >= N) st_row = N - 1;
  const _Float16* Abase = Af16 + (size_t)st_row * K_TOT + ((t >> 4) & 3) * 8;

  const size_t bfrag = (size_t)(w * 64 + (lane & 15)) * 32 + (lane >> 4) * 8;
  const _Float16* BhiP = Bhi + bfrag;
  // ct stride = 512 halves; ks stride = 8192 halves

  // stage the whole A panel (16 x 16B per thread, coalesced)
#pragma unroll
  for (int ks = 0; ks < 16; ++ks)
    *reinterpret_cast<f16x8*>(&Apan[(ks * 256 + t) * 8]) =
        *reinterpret_cast<const f16x8*>(Abase + ks * 32);

  // B prefetch: 2 k-steps deep
  f16x8 bH[2][4];
#pragma unroll
  for (int ct = 0; ct < 4; ++ct) {
    bH[0][ct] = *reinterpret_cast<const f16x8*>(BhiP + ct * 512);
    bH[1][ct] = *reinterpret_cast<const f16x8*>(BhiP + 8192 + ct * 512);
  }
  __syncthreads();  // the only pre-epilogue barrier

#pragma unroll
  for (int ks = 0; ks < 16; ++ks) {
    f16x8 aH[4];
#pragma unroll
    for (int rt = 0; rt < 4; ++rt)
      aH[rt] = *reinterpret_cast<const f16x8*>(
          &Apan[(ks * 256 + rt * 64 + lane) * 8]);
    f16x8 bNext[4];
    if (ks < 14) {
#pragma unroll
      for (int ct = 0; ct < 4; ++ct)
        bNext[ct] = *reinterpret_cast<const f16x8*>(BhiP + (size_t)(ks + 2) * 8192 + ct * 512);
    }
#pragma unroll
    for (int ct = 0; ct < 4; ++ct)
#pragma unroll
      for (int rt = 0; rt < 4; ++rt)
        acc[rt][ct] = __builtin_amdgcn_mfma_f32_16x16x32_f16(aH[rt], bH[ks & 1][ct],
                                                             acc[rt][ct], 0, 0, 0);
    if (ks < 14) {
#pragma unroll
      for (int ct = 0; ct < 4; ++ct) bH[ks & 1][ct] = bNext[ct];
    }
  }

  float bv[4];
#pragma unroll
  for (int ct = 0; ct < 4; ++ct) bv[ct] = bias[w * 64 + ct * 16 + (lane & 15)];

#pragma unroll
  for (int rt = 0; rt < 4; ++rt)
#pragma unroll
    for (int i = 0; i < 4; ++i) {
      float ssv = 0.f;
#pragma unroll
      for (int ct = 0; ct < 4; ++ct) {
        float val = acc[rt][ct][i] + bv[ct];
        acc[rt][ct][i] = val;
        ssv += val * val;
      }
#pragma unroll
      for (int s = 1; s < 16; s <<= 1) ssv += __shfl_xor(ssv, s, 64);
      if ((lane & 15) == 0) ssb[rt * 16 + (lane >> 4) * 4 + i][w] = ssv;
    }
  __syncthreads();

#pragma unroll
  for (int rt = 0; rt < 4; ++rt)
#pragma unroll
    for (int i = 0; i < 4; ++i) {
      int rl = rt * 16 + (lane >> 4) * 4 + i;
      f32x4 s4 = *reinterpret_cast<const f32x4*>(&ssb[rl][0]);
      float ss = s4[0] + s4[1] + s4[2] + s4[3];
      int gr = row0 + rl;
      if (gr < N) {
        float scale = 1.0f / fmaxf(sqrtf(ss), 1e-12f);
#pragma unroll
        for (int ct = 0; ct < 4; ++ct)
          out[(size_t)gr * IN_F + w * 64 + ct * 16 + (lane & 15)] = acc[rt][ct][i] * scale;
      }
    }
}

extern "C" void kernel_launch(void* const* d_in, const int* in_sizes, int n_in,
                              void* d_out, int out_size, void* d_ws, size_t ws_size,
                              hipStream_t stream) {
  const float* x = (const float*)d_in[0];
  const int* ei = (const int*)d_in[1];
  const float* ew = (const float*)d_in[2];
  const float* Wself = (const float*)d_in[3];
  const float* Wneigh = (const float*)d_in[4];
  const float* bias = (const float*)d_in[5];
  float* out = (float*)d_out;

  const int N = in_sizes[0] / IN_F;
  const int E = in_sizes[2];

  // ws: Af16[N*512 f16] | Bhi | xq[N*64 u32] | edges[E u32] |
  //     counts[N] | offsets[N+1] | cursor[N] | bsums[128] | flag
  char* p = (char*)d_ws;
  _Float16* Af16 = (_Float16*)p;     p += (size_t)N * K_TOT * 2;
  _Float16* Bhi = (_Float16*)p;      p += (size_t)K_TOT * IN_F * 2;
  uint32_t* xq = (uint32_t*)p;       p += (size_t)N * IN_F;
  uint32_t* edges = (uint32_t*)p;    p += (size_t)E * 4;
  int* counts = (int*)p;             p += (size_t)N * 4;
  int* offsets = (int*)p;            p += (size_t)(N + 1) * 4;
  int* cursor = (int*)p;             p += (size_t)N * 4;
  int* bsums = (int*)p;              p += 128 * 4;
  int* flag = (int*)p;

  const int nconv = (int)(((size_t)N * IN_F + 4095) / 4096);
  const int nhist = (E + 255) / 256;
  const int nb = (N + 1023) / 1024;
  const int nper = (N + 7) / 8;  // nodes per XCD bucket

  hipMemsetAsync(counts, 0, (size_t)N * sizeof(int), stream);

  init_kernel<<<512 + nconv + nhist + 1, 256, 0, stream>>>(
      x, Wself, Wneigh, ei, Bhi, xq, Af16, counts, flag, N, E, nconv, nhist);
  scan1_kernel<<<nb, 1024, 0, stream>>>(counts, offsets, bsums, N);
  scan23_kernel<<<(N + 255) / 256, 256, 0, stream>>>(offsets, bsums, cursor, N, E, nb);
  fill_kernel<<<((E + 255) / 256) * 8, 256, 0, stream>>>(ei, ew, flag, cursor, edges,
                                                         E, nper);
  aggregate_fp8_kernel<<<(N + 3) / 4, 256, 0, stream>>>(xq, offsets, edges, Af16, N);
  gemm_norm_kernel<<<(N + GR - 1) / GR, 256, 0, stream>>>(Af16, Bhi, bias, out, N);
}

// Round 14
// 302.488 us; speedup vs baseline: 1.2457x; 1.0962x over previous
//
#include <hip/hip_runtime.h>
#include <hip/hip_bf16.h>
#include <stdint.h>

#define IN_F 256
#define K_TOT 512
#define GR 64   // rows per gemm block

typedef __attribute__((ext_vector_type(8))) _Float16 f16x8;
typedef __attribute__((ext_vector_type(4))) _Float16 f16x4;
typedef __attribute__((ext_vector_type(4))) float f32x4;
typedef __attribute__((ext_vector_type(2))) float f32x2;

#if __has_builtin(__builtin_amdgcn_cvt_pk_f32_fp8) && __has_builtin(__builtin_amdgcn_cvt_pk_fp8_f32)
#define HW_FP8 1
#endif

// ---- fp8 e4m3 helpers (HW cvt with software RNE fallback) ----
__device__ __forceinline__ float fp8_dec1(uint32_t b) {
  union { uint16_t u; _Float16 h; } cv;
  cv.u = (uint16_t)((b & 0x7F) << 7);
  float v = (float)cv.h * 256.0f;
  return (b & 0x80) ? -v : v;
}
__device__ __forceinline__ uint32_t fp8_enc1(float f) {
  union { _Float16 h; uint16_t u; } cv;
  cv.h = (_Float16)(f * (1.0f / 256.0f));
  uint32_t s = (cv.u >> 8) & 0x80;
  uint32_t t = cv.u & 0x7FFF;
  uint32_t r = (t + 0x3F + ((t >> 7) & 1)) >> 7;  // RNE at 3-bit mantissa
  if (r > 0x7E) r = 0x7E;                          // clamp to 448
  return s | r;
}
__device__ __forceinline__ void fp8x4_dec(uint32_t w, float4& o) {
#ifdef HW_FP8
  f32x2 lo = __builtin_amdgcn_cvt_pk_f32_fp8((int)w, false);
  f32x2 hi = __builtin_amdgcn_cvt_pk_f32_fp8((int)w, true);
  o.x = lo[0]; o.y = lo[1]; o.z = hi[0]; o.w = hi[1];
#else
  o.x = fp8_dec1(w & 0xFF); o.y = fp8_dec1((w >> 8) & 0xFF);
  o.z = fp8_dec1((w >> 16) & 0xFF); o.w = fp8_dec1(w >> 24);
#endif
}
__device__ __forceinline__ uint32_t fp8x4_enc(float a, float b, float c, float d) {
#ifdef HW_FP8
  int r = __builtin_amdgcn_cvt_pk_fp8_f32(a, b, 0, false);
  r = __builtin_amdgcn_cvt_pk_fp8_f32(c, d, r, true);
  return (uint32_t)r;
#else
  return fp8_enc1(a) | (fp8_enc1(b) << 8) | (fp8_enc1(c) << 16) | (fp8_enc1(d) << 24);
#endif
}

// ---- fused init: build Bhi | x->(fp8 xq + f16 Af16 cols 0..255) | hist
//      (self-detecting i64) | detect i64 flag (for fill) ----
__global__ void init_kernel(const float* __restrict__ x,
                            const float* __restrict__ Ws,
                            const float* __restrict__ Wn,
                            const int* __restrict__ ei,
                            _Float16* __restrict__ Bhi,
                            uint32_t* __restrict__ xq, _Float16* __restrict__ Af16,
                            int* __restrict__ counts,
                            int* __restrict__ flag, int N, int E,
                            int nconv, int nhist) {
  __shared__ int bad_s[256];
  const int b = blockIdx.x;
  const int t = threadIdx.x;
  if (b < 512) {
    int idx = b * 256 + t;  // 0..131071
    int j = idx >> 9;
    int k = idx & 511;
    float v = (k < IN_F) ? Ws[j * IN_F + k] : Wn[j * IN_F + (k - IN_F)];
    size_t addr = ((size_t)(k >> 5) * 256 + j) * 32 + (k & 31);
    Bhi[addr] = (_Float16)v;
  } else if (b < 512 + nconv) {
    size_t base = (size_t)(b - 512) * 4096 + (size_t)t * 16;
    size_t tot = (size_t)N * IN_F;
    if (base + 16 <= tot) {
      const float4* x4 = reinterpret_cast<const float4*>(x + base);
      float4 v0 = x4[0], v1 = x4[1], v2 = x4[2], v3 = x4[3];
      uint4 o;
      o.x = fp8x4_enc(v0.x, v0.y, v0.z, v0.w);
      o.y = fp8x4_enc(v1.x, v1.y, v1.z, v1.w);
      o.z = fp8x4_enc(v2.x, v2.y, v2.z, v2.w);
      o.w = fp8x4_enc(v3.x, v3.y, v3.z, v3.w);
      *reinterpret_cast<uint4*>(xq + base / 4) = o;
      size_t row = base >> 8;
      int col = (int)(base & 255);
      f16x8 h0 = {(_Float16)v0.x, (_Float16)v0.y, (_Float16)v0.z, (_Float16)v0.w,
                  (_Float16)v1.x, (_Float16)v1.y, (_Float16)v1.z, (_Float16)v1.w};
      f16x8 h1 = {(_Float16)v2.x, (_Float16)v2.y, (_Float16)v2.z, (_Float16)v2.w,
                  (_Float16)v3.x, (_Float16)v3.y, (_Float16)v3.z, (_Float16)v3.w};
      _Float16* dst = Af16 + row * K_TOT + col;
      *reinterpret_cast<f16x8*>(dst) = h0;
      *reinterpret_cast<f16x8*>(dst + 8) = h1;
    }
  } else if (b < 512 + nconv + nhist) {
    int bad = 0;
#pragma unroll
    for (int p = 0; p < 8; ++p)
      if (ei[2 * (t + p * 256) + 1] != 0) bad = 1;
    bad_s[t] = bad;
    __syncthreads();
    for (int s = 128; s > 0; s >>= 1) {
      if (t < s) bad_s[t] |= bad_s[t + s];
      __syncthreads();
    }
    int is64 = (bad_s[0] == 0);
    int e = (b - 512 - nconv) * 256 + t;
    if (e < E) {
      int dst = is64 ? ei[2 * (E + e)] : ei[E + e];
      atomicAdd(counts + dst, 1);
    }
  } else {
    int bad = 0;
#pragma unroll
    for (int p = 0; p < 8; ++p) {
      int i = t + p * 256;
      if (ei[2 * i + 1] != 0) bad = 1;
    }
    bad_s[t] = bad;
    __syncthreads();
    for (int s = 128; s > 0; s >>= 1) {
      if (t < s) bad_s[t] |= bad_s[t + s];
      __syncthreads();
    }
    if (t == 0) *flag = (bad_s[0] == 0) ? 1 : 0;
  }
}

__global__ void scan1_kernel(const int* __restrict__ counts, int* __restrict__ offsets,
                             int* __restrict__ bsums, int N) {
  __shared__ int buf[1024];
  int t = threadIdx.x;
  int i = blockIdx.x * 1024 + t;
  int v = (i < N) ? counts[i] : 0;
  buf[t] = v;
  __syncthreads();
  for (int s = 1; s < 1024; s <<= 1) {
    int add = (t >= s) ? buf[t - s] : 0;
    __syncthreads();
    buf[t] += add;
    __syncthreads();
  }
  if (i < N) offsets[i] = buf[t] - v;
  if (t == 1023) bsums[blockIdx.x] = buf[1023];
}

__global__ void scan23_kernel(int* __restrict__ offsets, const int* __restrict__ bsums,
                              int* __restrict__ cursor, int N, int E, int nb) {
  __shared__ int sb[128];
  int t = threadIdx.x;
  int v = 0;
  if (t < 128) {
    v = (t < nb) ? bsums[t] : 0;
    sb[t] = v;
  }
  __syncthreads();
  for (int s = 1; s < 128; s <<= 1) {
    int add = 0;
    if (t < 128 && t >= s) add = sb[t - s];
    __syncthreads();
    if (t < 128) sb[t] += add;
    __syncthreads();
  }
  if (t < 128) sb[t] -= v;  // exclusive
  __syncthreads();
  int i = blockIdx.x * 256 + t;
  if (i < N) {
    int o = offsets[i] + sb[i >> 10];
    offsets[i] = o;
    cursor[i] = o;
  }
  if (i == 0) offsets[N] = E;
}

// XCD-bucketed CSR fill, 4B packed entries (src<<15 | w15). Range-compare
// instead of integer divide for bucket test.
__global__ void fill_kernel(const int* __restrict__ ei, const float* __restrict__ ew,
                            const int* __restrict__ flag, int* __restrict__ cursor,
                            uint32_t* __restrict__ edges, int E, int nper) {
  int q = blockIdx.x & 7;
  int e = (blockIdx.x >> 3) * 256 + threadIdx.x;
  if (e >= E) return;
  int is64 = *flag;
  int dst = is64 ? ei[2 * (E + e)] : ei[E + e];
  if ((unsigned)(dst - q * nper) >= (unsigned)nper) return;
  int src = is64 ? ei[2 * e] : ei[e];
  uint32_t w15 = (uint32_t)__float2int_rn(ew[e] * 32767.0f);
  int pos = atomicAdd(cursor + dst, 1);
  edges[pos] = ((uint32_t)src << 15) | w15;
}

// One wave per dst node, fp8 gather with 32-bit element offsets (SGPR-base +
// voffset addressing, no per-lane 64-bit carry chain); writes f16 result into
// Af16 cols 256..511.
__launch_bounds__(256)
__global__ void aggregate_fp8_kernel(const uint32_t* __restrict__ xq,
                                     const int* __restrict__ offsets,
                                     const uint32_t* __restrict__ edges,
                                     _Float16* __restrict__ Af16, int N) {
  int wid = blockIdx.x * 4 + (threadIdx.x >> 6);
  if (wid >= N) return;
  uint32_t lane = threadIdx.x & 63;
  int beg = offsets[wid];
  int end = offsets[wid + 1];
  float4 acc = {0.f, 0.f, 0.f, 0.f};
  float ws = 0.f;
  const float wscale = 1.0f / 32767.0f;
  int e = beg;
  for (; e + 3 < end; e += 4) {
    uint32_t n0 = edges[e], n1 = edges[e + 1], n2 = edges[e + 2], n3 = edges[e + 3];
    float w0 = (float)(n0 & 0x7FFF) * wscale, w1 = (float)(n1 & 0x7FFF) * wscale;
    float w2 = (float)(n2 & 0x7FFF) * wscale, w3 = (float)(n3 & 0x7FFF) * wscale;
    uint32_t o0 = (n0 >> 15) * 64u + lane;
    uint32_t o1 = (n1 >> 15) * 64u + lane;
    uint32_t o2 = (n2 >> 15) * 64u + lane;
    uint32_t o3 = (n3 >> 15) * 64u + lane;
    uint32_t q0 = xq[o0], q1 = xq[o1], q2 = xq[o2], q3 = xq[o3];
    float4 f0, f1, f2, f3;
    fp8x4_dec(q0, f0); fp8x4_dec(q1, f1); fp8x4_dec(q2, f2); fp8x4_dec(q3, f3);
    acc.x += f0.x * w0 + f1.x * w1 + f2.x * w2 + f3.x * w3;
    acc.y += f0.y * w0 + f1.y * w1 + f2.y * w2 + f3.y * w3;
    acc.z += f0.z * w0 + f1.z * w1 + f2.z * w2 + f3.z * w3;
    acc.w += f0.w * w0 + f1.w * w1 + f2.w * w2 + f3.w * w3;
    ws += w0 + w1 + w2 + w3;
  }
  for (; e < end; ++e) {
    uint32_t n0 = edges[e];
    float w0 = (float)(n0 & 0x7FFF) * wscale;
    uint32_t q0 = xq[(n0 >> 15) * 64u + lane];
    float4 f0;
    fp8x4_dec(q0, f0);
    acc.x += f0.x * w0; acc.y += f0.y * w0; acc.z += f0.z * w0; acc.w += f0.w * w0;
    ws += w0;
  }
  float inv = 1.f / fmaxf(ws, 1e-8f);
  f16x4 o = {(_Float16)(acc.x * inv), (_Float16)(acc.y * inv),
             (_Float16)(acc.z * inv), (_Float16)(acc.w * inv)};
  *reinterpret_cast<f16x4*>(Af16 + (size_t)wid * K_TOT + IN_F + lane * 4) = o;
}

// Pipelined MFMA GEMM + L2-norm (r11 version, verbatim). A frag-major
// double-buffered LDS; B register-prefetched 2 k-steps ahead from L2.
__launch_bounds__(256)
__global__ void gemm_norm_kernel(const _Float16* __restrict__ Af16,
                                 const _Float16* __restrict__ Bhi,
                                 const float* __restrict__ bias,
                                 float* __restrict__ out, int N) {
  const int t = threadIdx.x;
  const int lane = t & 63;
  const int w = t >> 6;
  const int row0 = blockIdx.x * GR;

  __shared__ _Float16 Ah[2][256 * 8];  // frag-major, double-buffered
  __shared__ float ssb[GR][4];

  f32x4 acc[4][4];
#pragma unroll
  for (int rt = 0; rt < 4; ++rt)
#pragma unroll
    for (int ct = 0; ct < 4; ++ct) acc[rt][ct] = (f32x4){0.f, 0.f, 0.f, 0.f};

  int st_row = row0 + (t >> 6) * 16 + (t & 15);
  if (st_row >= N) st_row = N - 1;
  const _Float16* Abase = Af16 + (size_t)st_row * K_TOT + ((t >> 4) & 3) * 8;

  const size_t bfrag = (size_t)(w * 64 + (lane & 15)) * 32 + (lane >> 4) * 8;
  const _Float16* BhiP = Bhi + bfrag;
  // ct stride = 512 halves; ks stride = 8192 halves

  // prologue: A(0)->LDS0, A(1)->reg; B(0),B(1)->regs (2-deep)
  *reinterpret_cast<f16x8*>(&Ah[0][t * 8]) = *reinterpret_cast<const f16x8*>(Abase);
  f16x8 a_next = *reinterpret_cast<const f16x8*>(Abase + 32);
  f16x8 bH[2][4];
#pragma unroll
  for (int ct = 0; ct < 4; ++ct) {
    bH[0][ct] = *reinterpret_cast<const f16x8*>(BhiP + ct * 512);
    bH[1][ct] = *reinterpret_cast<const f16x8*>(BhiP + 8192 + ct * 512);
  }
  __syncthreads();

#pragma unroll
  for (int ks = 0; ks < 16; ++ks) {
    f16x8 aH[4];
#pragma unroll
    for (int rt = 0; rt < 4; ++rt)
      aH[rt] = *reinterpret_cast<const f16x8*>(&Ah[ks & 1][(rt * 64 + lane) * 8]);
    f16x8 bNext[4];
    if (ks < 14) {
#pragma unroll
      for (int ct = 0; ct < 4; ++ct)
        bNext[ct] = *reinterpret_cast<const f16x8*>(BhiP + (size_t)(ks + 2) * 8192 + ct * 512);
    }
    if (ks < 15)
      *reinterpret_cast<f16x8*>(&Ah[(ks + 1) & 1][t * 8]) = a_next;
    if (ks < 14)
      a_next = *reinterpret_cast<const f16x8*>(Abase + (size_t)(ks + 2) * 32);
#pragma unroll
    for (int ct = 0; ct < 4; ++ct)
#pragma unroll
      for (int rt = 0; rt < 4; ++rt)
        acc[rt][ct] = __builtin_amdgcn_mfma_f32_16x16x32_f16(aH[rt], bH[ks & 1][ct], acc[rt][ct], 0, 0, 0);
    if (ks < 14) {
#pragma unroll
      for (int ct = 0; ct < 4; ++ct) bH[ks & 1][ct] = bNext[ct];
    }
    __syncthreads();
  }

  float bv[4];
#pragma unroll
  for (int ct = 0; ct < 4; ++ct) bv[ct] = bias[w * 64 + ct * 16 + (lane & 15)];

#pragma unroll
  for (int rt = 0; rt < 4; ++rt)
#pragma unroll
    for (int i = 0; i < 4; ++i) {
      float ssv = 0.f;
#pragma unroll
      for (int ct = 0; ct < 4; ++ct) {
        float val = acc[rt][ct][i] + bv[ct];
        acc[rt][ct][i] = val;
        ssv += val * val;
      }
#pragma unroll
      for (int s = 1; s < 16; s <<= 1) ssv += __shfl_xor(ssv, s, 64);
      if ((lane & 15) == 0) ssb[rt * 16 + (lane >> 4) * 4 + i][w] = ssv;
    }
  __syncthreads();

#pragma unroll
  for (int rt = 0; rt < 4; ++rt)
#pragma unroll
    for (int i = 0; i < 4; ++i) {
      int rl = rt * 16 + (lane >> 4) * 4 + i;
      f32x4 s4 = *reinterpret_cast<const f32x4*>(&ssb[rl][0]);
      float ss = s4[0] + s4[1] + s4[2] + s4[3];
      int gr = row0 + rl;
      if (gr < N) {
        float scale = 1.0f / fmaxf(sqrtf(ss), 1e-12f);
#pragma unroll
        for (int ct = 0; ct < 4; ++ct)
          out[(size_t)gr * IN_F + w * 64 + ct * 16 + (lane & 15)] = acc[rt][ct][i] * scale;
      }
    }
}

extern "C" void kernel_launch(void* const* d_in, const int* in_sizes, int n_in,
                              void* d_out, int out_size, void* d_ws, size_t ws_size,
                              hipStream_t stream) {
  const float* x = (const float*)d_in[0];
  const int* ei = (const int*)d_in[1];
  const float* ew = (const float*)d_in[2];
  const float* Wself = (const float*)d_in[3];
  const float* Wneigh = (const float*)d_in[4];
  const float* bias = (const float*)d_in[5];
  float* out = (float*)d_out;

  const int N = in_sizes[0] / IN_F;
  const int E = in_sizes[2];

  // ws: Af16[N*512 f16] | Bhi | xq[N*64 u32] | edges[E u32] |
  //     counts[N] | offsets[N+1] | cursor[N] | bsums[128] | flag
  char* p = (char*)d_ws;
  _Float16* Af16 = (_Float16*)p;     p += (size_t)N * K_TOT * 2;
  _Float16* Bhi = (_Float16*)p;      p += (size_t)K_TOT * IN_F * 2;
  uint32_t* xq = (uint32_t*)p;       p += (size_t)N * IN_F;
  uint32_t* edges = (uint32_t*)p;    p += (size_t)E * 4;
  int* counts = (int*)p;             p += (size_t)N * 4;
  int* offsets = (int*)p;            p += (size_t)(N + 1) * 4;
  int* cursor = (int*)p;             p += (size_t)N * 4;
  int* bsums = (int*)p;              p += 128 * 4;
  int* flag = (int*)p;

  const int nconv = (int)(((size_t)N * IN_F + 4095) / 4096);
  const int nhist = (E + 255) / 256;
  const int nb = (N + 1023) / 1024;
  const int nper = (N + 7) / 8;  // nodes per XCD bucket

  hipMemsetAsync(counts, 0, (size_t)N * sizeof(int), stream);

  init_kernel<<<512 + nconv + nhist + 1, 256, 0, stream>>>(
      x, Wself, Wneigh, ei, Bhi, xq, Af16, counts, flag, N, E, nconv, nhist);
  scan1_kernel<<<nb, 1024, 0, stream>>>(counts, offsets, bsums, N);
  scan23_kernel<<<(N + 255) / 256, 256, 0, stream>>>(offsets, bsums, cursor, N, E, nb);
  fill_kernel<<<((E + 255) / 256) * 8, 256, 0, stream>>>(ei, ew, flag, cursor, edges,
                                                         E, nper);
  aggregate_fp8_kernel<<<(N + 3) / 4, 256, 0, stream>>>(xq, offsets, edges, Af16, N);
  gemm_norm_kernel<<<(N + GR - 1) / GR, 256, 0, stream>>>(Af16, Bhi, bias, out, N);
}

// Round 15
// 281.476 us; speedup vs baseline: 1.3387x; 1.0747x over previous
//
#include <hip/hip_runtime.h>
#include <hip/hip_bf16.h>
#include <stdint.h>

#define IN_F 256
#define K_TOT 512
#define GR 64   // rows per gemm block

typedef __attribute__((ext_vector_type(8))) _Float16 f16x8;
typedef __attribute__((ext_vector_type(4))) _Float16 f16x4;
typedef __attribute__((ext_vector_type(4))) float f32x4;
typedef __attribute__((ext_vector_type(2))) float f32x2;

#if __has_builtin(__builtin_amdgcn_cvt_pk_f32_fp8) && __has_builtin(__builtin_amdgcn_cvt_pk_fp8_f32)
#define HW_FP8 1
#endif

// ---- fp8 e4m3 helpers (HW cvt with software RNE fallback) ----
__device__ __forceinline__ float fp8_dec1(uint32_t b) {
  union { uint16_t u; _Float16 h; } cv;
  cv.u = (uint16_t)((b & 0x7F) << 7);
  float v = (float)cv.h * 256.0f;
  return (b & 0x80) ? -v : v;
}
__device__ __forceinline__ uint32_t fp8_enc1(float f) {
  union { _Float16 h; uint16_t u; } cv;
  cv.h = (_Float16)(f * (1.0f / 256.0f));
  uint32_t s = (cv.u >> 8) & 0x80;
  uint32_t t = cv.u & 0x7FFF;
  uint32_t r = (t + 0x3F + ((t >> 7) & 1)) >> 7;  // RNE at 3-bit mantissa
  if (r > 0x7E) r = 0x7E;                          // clamp to 448
  return s | r;
}
__device__ __forceinline__ void fp8x4_dec(uint32_t w, float4& o) {
#ifdef HW_FP8
  f32x2 lo = __builtin_amdgcn_cvt_pk_f32_fp8((int)w, false);
  f32x2 hi = __builtin_amdgcn_cvt_pk_f32_fp8((int)w, true);
  o.x = lo[0]; o.y = lo[1]; o.z = hi[0]; o.w = hi[1];
#else
  o.x = fp8_dec1(w & 0xFF); o.y = fp8_dec1((w >> 8) & 0xFF);
  o.z = fp8_dec1((w >> 16) & 0xFF); o.w = fp8_dec1(w >> 24);
#endif
}
__device__ __forceinline__ uint32_t fp8x4_enc(float a, float b, float c, float d) {
#ifdef HW_FP8
  int r = __builtin_amdgcn_cvt_pk_fp8_f32(a, b, 0, false);
  r = __builtin_amdgcn_cvt_pk_fp8_f32(c, d, r, true);
  return (uint32_t)r;
#else
  return fp8_enc1(a) | (fp8_enc1(b) << 8) | (fp8_enc1(c) << 16) | (fp8_enc1(d) << 24);
#endif
}

// ---- fused init: build Bhi | x->(fp8 xq + f16 Af16 cols 0..255) | hist ----
// conv and hist blocks are ROUND-ROBIN interleaved so the atomic-bound hist
// work co-resides with (and hides under) the streaming conv work, instead of
// forming a serial low-BW tail (r14: init 113us, BW 1.6TB/s, VALU 3%).
__global__ void init_kernel(const float* __restrict__ x,
                            const float* __restrict__ Ws,
                            const float* __restrict__ Wn,
                            const int* __restrict__ ei,
                            _Float16* __restrict__ Bhi,
                            uint32_t* __restrict__ xq, _Float16* __restrict__ Af16,
                            int* __restrict__ counts,
                            int* __restrict__ flag, int N, int E,
                            int nconv, int nhist) {
  __shared__ int bad_s[256];
  const int b = blockIdx.x;
  const int t = threadIdx.x;
  if (b < 512) {
    int idx = b * 256 + t;  // 0..131071
    int j = idx >> 9;
    int k = idx & 511;
    float v = (k < IN_F) ? Ws[j * IN_F + k] : Wn[j * IN_F + (k - IN_F)];
    size_t addr = ((size_t)(k >> 5) * 256 + j) * 32 + (k & 31);
    Bhi[addr] = (_Float16)v;
  } else if (b < 512 + nconv + nhist) {
    // round-robin role assignment over the mixed region
    int m = b - 512;
    int npair = 2 * (nconv < nhist ? nconv : nhist);
    int role, ci;
    if (m < npair) { role = m & 1; ci = m >> 1; }
    else if (nconv > nhist) { role = 0; ci = nhist + (m - npair); }
    else { role = 1; ci = nconv + (m - npair); }
    if (role == 0) {
      // ---- conv block ci ----
      size_t base = (size_t)ci * 4096 + (size_t)t * 16;
      size_t tot = (size_t)N * IN_F;
      if (base + 16 <= tot) {
        const float4* x4 = reinterpret_cast<const float4*>(x + base);
        float4 v0 = x4[0], v1 = x4[1], v2 = x4[2], v3 = x4[3];
        uint4 o;
        o.x = fp8x4_enc(v0.x, v0.y, v0.z, v0.w);
        o.y = fp8x4_enc(v1.x, v1.y, v1.z, v1.w);
        o.z = fp8x4_enc(v2.x, v2.y, v2.z, v2.w);
        o.w = fp8x4_enc(v3.x, v3.y, v3.z, v3.w);
        *reinterpret_cast<uint4*>(xq + base / 4) = o;
        size_t row = base >> 8;
        int col = (int)(base & 255);
        f16x8 h0 = {(_Float16)v0.x, (_Float16)v0.y, (_Float16)v0.z, (_Float16)v0.w,
                    (_Float16)v1.x, (_Float16)v1.y, (_Float16)v1.z, (_Float16)v1.w};
        f16x8 h1 = {(_Float16)v2.x, (_Float16)v2.y, (_Float16)v2.z, (_Float16)v2.w,
                    (_Float16)v3.x, (_Float16)v3.y, (_Float16)v3.z, (_Float16)v3.w};
        _Float16* dst = Af16 + row * K_TOT + col;
        *reinterpret_cast<f16x8*>(dst) = h0;
        *reinterpret_cast<f16x8*>(dst + 8) = h1;
      }
    } else {
      // ---- hist block ci (self-detecting i64 layout) ----
      int bad = 0;
#pragma unroll
      for (int p = 0; p < 8; ++p)
        if (ei[2 * (t + p * 256) + 1] != 0) bad = 1;
      bad_s[t] = bad;
      __syncthreads();
      for (int s = 128; s > 0; s >>= 1) {
        if (t < s) bad_s[t] |= bad_s[t + s];
        __syncthreads();
      }
      int is64 = (bad_s[0] == 0);
      int e = ci * 256 + t;
      if (e < E) {
        int dst = is64 ? ei[2 * (E + e)] : ei[E + e];
        atomicAdd(counts + dst, 1);
      }
    }
  } else {
    int bad = 0;
#pragma unroll
    for (int p = 0; p < 8; ++p) {
      int i = t + p * 256;
      if (ei[2 * i + 1] != 0) bad = 1;
    }
    bad_s[t] = bad;
    __syncthreads();
    for (int s = 128; s > 0; s >>= 1) {
      if (t < s) bad_s[t] |= bad_s[t + s];
      __syncthreads();
    }
    if (t == 0) *flag = (bad_s[0] == 0) ? 1 : 0;
  }
}

__global__ void scan1_kernel(const int* __restrict__ counts, int* __restrict__ offsets,
                             int* __restrict__ bsums, int N) {
  __shared__ int buf[1024];
  int t = threadIdx.x;
  int i = blockIdx.x * 1024 + t;
  int v = (i < N) ? counts[i] : 0;
  buf[t] = v;
  __syncthreads();
  for (int s = 1; s < 1024; s <<= 1) {
    int add = (t >= s) ? buf[t - s] : 0;
    __syncthreads();
    buf[t] += add;
    __syncthreads();
  }
  if (i < N) offsets[i] = buf[t] - v;
  if (t == 1023) bsums[blockIdx.x] = buf[1023];
}

__global__ void scan23_kernel(int* __restrict__ offsets, const int* __restrict__ bsums,
                              int* __restrict__ cursor, int N, int E, int nb) {
  __shared__ int sb[128];
  int t = threadIdx.x;
  int v = 0;
  if (t < 128) {
    v = (t < nb) ? bsums[t] : 0;
    sb[t] = v;
  }
  __syncthreads();
  for (int s = 1; s < 128; s <<= 1) {
    int add = 0;
    if (t < 128 && t >= s) add = sb[t - s];
    __syncthreads();
    if (t < 128) sb[t] += add;
    __syncthreads();
  }
  if (t < 128) sb[t] -= v;  // exclusive
  __syncthreads();
  int i = blockIdx.x * 256 + t;
  if (i < N) {
    int o = offsets[i] + sb[i >> 10];
    offsets[i] = o;
    cursor[i] = o;
  }
  if (i == 0) offsets[N] = E;
}

// XCD-bucketed CSR fill, 4B packed entries (src<<15 | w15).
__global__ void fill_kernel(const int* __restrict__ ei, const float* __restrict__ ew,
                            const int* __restrict__ flag, int* __restrict__ cursor,
                            uint32_t* __restrict__ edges, int E, int nper) {
  int q = blockIdx.x & 7;
  int e = (blockIdx.x >> 3) * 256 + threadIdx.x;
  if (e >= E) return;
  int is64 = *flag;
  int dst = is64 ? ei[2 * (E + e)] : ei[E + e];
  if ((unsigned)(dst - q * nper) >= (unsigned)nper) return;
  int src = is64 ? ei[2 * e] : ei[e];
  uint32_t w15 = (uint32_t)__float2int_rn(ew[e] * 32767.0f);
  int pos = atomicAdd(cursor + dst, 1);
  edges[pos] = ((uint32_t)src << 15) | w15;
}

// One wave per dst node, fp8 gather, 8-deep load batching (issue all 8 edge
// loads, then all 8 gathers -> 2x MLP vs 4-deep), 32-bit element offsets.
__launch_bounds__(256)
__global__ void aggregate_fp8_kernel(const uint32_t* __restrict__ xq,
                                     const int* __restrict__ offsets,
                                     const uint32_t* __restrict__ edges,
                                     _Float16* __restrict__ Af16, int N) {
  int wid = blockIdx.x * 4 + (threadIdx.x >> 6);
  if (wid >= N) return;
  uint32_t lane = threadIdx.x & 63;
  int beg = offsets[wid];
  int end = offsets[wid + 1];
  float4 acc = {0.f, 0.f, 0.f, 0.f};
  float ws = 0.f;
  const float wscale = 1.0f / 32767.0f;
  int e = beg;
  for (; e + 7 < end; e += 8) {
    uint32_t n[8];
#pragma unroll
    for (int j = 0; j < 8; ++j) n[j] = edges[e + j];
    uint32_t q[8];
#pragma unroll
    for (int j = 0; j < 8; ++j) q[j] = xq[(n[j] >> 15) * 64u + lane];
#pragma unroll
    for (int j = 0; j < 8; ++j) {
      float wj = (float)(n[j] & 0x7FFF) * wscale;
      float4 fj;
      fp8x4_dec(q[j], fj);
      acc.x += fj.x * wj; acc.y += fj.y * wj;
      acc.z += fj.z * wj; acc.w += fj.w * wj;
      ws += wj;
    }
  }
  for (; e < end; ++e) {
    uint32_t n0 = edges[e];
    float w0 = (float)(n0 & 0x7FFF) * wscale;
    uint32_t q0 = xq[(n0 >> 15) * 64u + lane];
    float4 f0;
    fp8x4_dec(q0, f0);
    acc.x += f0.x * w0; acc.y += f0.y * w0; acc.z += f0.z * w0; acc.w += f0.w * w0;
    ws += w0;
  }
  float inv = 1.f / fmaxf(ws, 1e-8f);
  f16x4 o = {(_Float16)(acc.x * inv), (_Float16)(acc.y * inv),
             (_Float16)(acc.z * inv), (_Float16)(acc.w * inv)};
  *reinterpret_cast<f16x4*>(Af16 + (size_t)wid * K_TOT + IN_F + lane * 4) = o;
}

// Pipelined MFMA GEMM + L2-norm (r11 version, frozen). A frag-major
// double-buffered LDS; B register-prefetched 2 k-steps ahead from L2.
__launch_bounds__(256)
__global__ void gemm_norm_kernel(const _Float16* __restrict__ Af16,
                                 const _Float16* __restrict__ Bhi,
                                 const float* __restrict__ bias,
                                 float* __restrict__ out, int N) {
  const int t = threadIdx.x;
  const int lane = t & 63;
  const int w = t >> 6;
  const int row0 = blockIdx.x * GR;

  __shared__ _Float16 Ah[2][256 * 8];  // frag-major, double-buffered
  __shared__ float ssb[GR][4];

  f32x4 acc[4][4];
#pragma unroll
  for (int rt = 0; rt < 4; ++rt)
#pragma unroll
    for (int ct = 0; ct < 4; ++ct) acc[rt][ct] = (f32x4){0.f, 0.f, 0.f, 0.f};

  int st_row = row0 + (t >> 6) * 16 + (t & 15);
  if (st_row >= N) st_row = N - 1;
  const _Float16* Abase = Af16 + (size_t)st_row * K_TOT + ((t >> 4) & 3) * 8;

  const size_t bfrag = (size_t)(w * 64 + (lane & 15)) * 32 + (lane >> 4) * 8;
  const _Float16* BhiP = Bhi + bfrag;
  // ct stride = 512 halves; ks stride = 8192 halves

  // prologue: A(0)->LDS0, A(1)->reg; B(0),B(1)->regs (2-deep)
  *reinterpret_cast<f16x8*>(&Ah[0][t * 8]) = *reinterpret_cast<const f16x8*>(Abase);
  f16x8 a_next = *reinterpret_cast<const f16x8*>(Abase + 32);
  f16x8 bH[2][4];
#pragma unroll
  for (int ct = 0; ct < 4; ++ct) {
    bH[0][ct] = *reinterpret_cast<const f16x8*>(BhiP + ct * 512);
    bH[1][ct] = *reinterpret_cast<const f16x8*>(BhiP + 8192 + ct * 512);
  }
  __syncthreads();

#pragma unroll
  for (int ks = 0; ks < 16; ++ks) {
    f16x8 aH[4];
#pragma unroll
    for (int rt = 0; rt < 4; ++rt)
      aH[rt] = *reinterpret_cast<const f16x8*>(&Ah[ks & 1][(rt * 64 + lane) * 8]);
    f16x8 bNext[4];
    if (ks < 14) {
#pragma unroll
      for (int ct = 0; ct < 4; ++ct)
        bNext[ct] = *reinterpret_cast<const f16x8*>(BhiP + (size_t)(ks + 2) * 8192 + ct * 512);
    }
    if (ks < 15)
      *reinterpret_cast<f16x8*>(&Ah[(ks + 1) & 1][t * 8]) = a_next;
    if (ks < 14)
      a_next = *reinterpret_cast<const f16x8*>(Abase + (size_t)(ks + 2) * 32);
#pragma unroll
    for (int ct = 0; ct < 4; ++ct)
#pragma unroll
      for (int rt = 0; rt < 4; ++rt)
        acc[rt][ct] = __builtin_amdgcn_mfma_f32_16x16x32_f16(aH[rt], bH[ks & 1][ct], acc[rt][ct], 0, 0, 0);
    if (ks < 14) {
#pragma unroll
      for (int ct = 0; ct < 4; ++ct) bH[ks & 1][ct] = bNext[ct];
    }
    __syncthreads();
  }

  float bv[4];
#pragma unroll
  for (int ct = 0; ct < 4; ++ct) bv[ct] = bias[w * 64 + ct * 16 + (lane & 15)];

#pragma unroll
  for (int rt = 0; rt < 4; ++rt)
#pragma unroll
    for (int i = 0; i < 4; ++i) {
      float ssv = 0.f;
#pragma unroll
      for (int ct = 0; ct < 4; ++ct) {
        float val = acc[rt][ct][i] + bv[ct];
        acc[rt][ct][i] = val;
        ssv += val * val;
      }
#pragma unroll
      for (int s = 1; s < 16; s <<= 1) ssv += __shfl_xor(ssv, s, 64);
      if ((lane & 15) == 0) ssb[rt * 16 + (lane >> 4) * 4 + i][w] = ssv;
    }
  __syncthreads();

#pragma unroll
  for (int rt = 0; rt < 4; ++rt)
#pragma unroll
    for (int i = 0; i < 4; ++i) {
      int rl = rt * 16 + (lane >> 4) * 4 + i;
      f32x4 s4 = *reinterpret_cast<const f32x4*>(&ssb[rl][0]);
      float ss = s4[0] + s4[1] + s4[2] + s4[3];
      int gr = row0 + rl;
      if (gr < N) {
        float scale = 1.0f / fmaxf(sqrtf(ss), 1e-12f);
#pragma unroll
        for (int ct = 0; ct < 4; ++ct)
          out[(size_t)gr * IN_F + w * 64 + ct * 16 + (lane & 15)] = acc[rt][ct][i] * scale;
      }
    }
}

extern "C" void kernel_launch(void* const* d_in, const int* in_sizes, int n_in,
                              void* d_out, int out_size, void* d_ws, size_t ws_size,
                              hipStream_t stream) {
  const float* x = (const float*)d_in[0];
  const int* ei = (const int*)d_in[1];
  const float* ew = (const float*)d_in[2];
  const float* Wself = (const float*)d_in[3];
  const float* Wneigh = (const float*)d_in[4];
  const float* bias = (const float*)d_in[5];
  float* out = (float*)d_out;

  const int N = in_sizes[0] / IN_F;
  const int E = in_sizes[2];

  // ws: Af16[N*512 f16] | Bhi | xq[N*64 u32] | edges[E u32] |
  //     counts[N] | offsets[N+1] | cursor[N] | bsums[128] | flag
  char* p = (char*)d_ws;
  _Float16* Af16 = (_Float16*)p;     p += (size_t)N * K_TOT * 2;
  _Float16* Bhi = (_Float16*)p;      p += (size_t)K_TOT * IN_F * 2;
  uint32_t* xq = (uint32_t*)p;       p += (size_t)N * IN_F;
  uint32_t* edges = (uint32_t*)p;    p += (size_t)E * 4;
  int* counts = (int*)p;             p += (size_t)N * 4;
  int* offsets = (int*)p;            p += (size_t)(N + 1) * 4;
  int* cursor = (int*)p;             p += (size_t)N * 4;
  int* bsums = (int*)p;              p += 128 * 4;
  int* flag = (int*)p;

  const int nconv = (int)(((size_t)N * IN_F + 4095) / 4096);
  const int nhist = (E + 255) / 256;
  const int nb = (N + 1023) / 1024;
  const int nper = (N + 7) / 8;  // nodes per XCD bucket

  hipMemsetAsync(counts, 0, (size_t)N * sizeof(int), stream);

  init_kernel<<<512 + nconv + nhist + 1, 256, 0, stream>>>(
      x, Wself, Wneigh, ei, Bhi, xq, Af16, counts, flag, N, E, nconv, nhist);
  scan1_kernel<<<nb, 1024, 0, stream>>>(counts, offsets, bsums, N);
  scan23_kernel<<<(N + 255) / 256, 256, 0, stream>>>(offsets, bsums, cursor, N, E, nb);
  fill_kernel<<<((E + 255) / 256) * 8, 256, 0, stream>>>(ei, ew, flag, cursor, edges,
                                                         E, nper);
  aggregate_fp8_kernel<<<(N + 3) / 4, 256, 0, stream>>>(xq, offsets, edges, Af16, N);
  gemm_norm_kernel<<<(N + GR - 1) / GR, 256, 0, stream>>>(Af16, Bhi, bias, out, N);
}